// Round 3
// baseline (682.368 us; speedup 1.0000x reference)
//
#include <hip/hip_runtime.h>
#include <stdint.h>

typedef short short8 __attribute__((ext_vector_type(8)));
typedef unsigned short ushort8 __attribute__((ext_vector_type(8)));
typedef unsigned short ushort4v __attribute__((ext_vector_type(4)));
typedef float f32x4 __attribute__((ext_vector_type(4)));

#define HD 2048
#define S_LEN 2048
#define NROWS 8192
#define N3 6144

typedef __attribute__((address_space(3))) void lds_void_t;
typedef __attribute__((address_space(1))) void g_void_t;

__device__ inline void gload_lds16(const void* g, void* l) {
    __builtin_amdgcn_global_load_lds((g_void_t*)g, (lds_void_t*)l, 16, 0, 0);
}

__device__ inline unsigned short f2bf(float f) {
    unsigned u = __float_as_uint(f);
    unsigned r = (u + 0x7FFFu + ((u >> 16) & 1u)) >> 16;
    return (unsigned short)r;
}
__device__ inline float bf2f(unsigned short h) {
    return __uint_as_float(((unsigned)h) << 16);
}

// ---------------- LayerNorm fp32 -> bf16 ----------------
__global__ __launch_bounds__(256) void ln_kernel(const float* __restrict__ x,
    const float* __restrict__ gamma, const float* __restrict__ beta,
    unsigned short* __restrict__ xn) {
    int row = blockIdx.x;
    const float* xr = x + (size_t)row * HD;
    int tid = threadIdx.x;
    float v[8];
    float4 a = *(const float4*)(xr + tid * 8);
    float4 b = *(const float4*)(xr + tid * 8 + 4);
    v[0]=a.x; v[1]=a.y; v[2]=a.z; v[3]=a.w; v[4]=b.x; v[5]=b.y; v[6]=b.z; v[7]=b.w;
    float s = 0.f, ss = 0.f;
#pragma unroll
    for (int e = 0; e < 8; e++) { s += v[e]; ss += v[e] * v[e]; }
    for (int off = 32; off > 0; off >>= 1) {
        s += __shfl_down(s, off);
        ss += __shfl_down(ss, off);
    }
    __shared__ float red[10];
    int wave = tid >> 6, lane = tid & 63;
    if (lane == 0) { red[wave] = s; red[4 + wave] = ss; }
    __syncthreads();
    if (tid == 0) {
        float S = red[0] + red[1] + red[2] + red[3];
        float SS = red[4] + red[5] + red[6] + red[7];
        float mu = S * (1.0f / HD);
        float var = SS * (1.0f / HD) - mu * mu;
        red[8] = mu;
        red[9] = rsqrtf(var + 1e-5f);
    }
    __syncthreads();
    float mu = red[8], rstd = red[9];
#pragma unroll
    for (int e = 0; e < 8; e++) {
        int c = tid * 8 + e;
        float val = (v[e] - mu) * rstd * gamma[c] + beta[c];
        xn[(size_t)row * HD + c] = f2bf(val);
    }
}

// ---------------- transpose + cast fp32 -> bf16 (both weights, one launch) ----
// x<192: qkv [2048,6144] -> w_t [6144,2048]; else o_proj [2048,2048] -> o_t.
__global__ __launch_bounds__(256) void transp_weights(const float* __restrict__ qkv,
    unsigned short* __restrict__ w_t, const float* __restrict__ o_proj,
    unsigned short* __restrict__ o_t) {
    __shared__ float tile[32][33];
    const float* src; unsigned short* dst; int ld_s, ld_d, bx;
    if (blockIdx.x < 192) { src = qkv; dst = w_t; ld_s = N3; ld_d = HD; bx = blockIdx.x; }
    else { src = o_proj; dst = o_t; ld_s = HD; ld_d = HD; bx = blockIdx.x - 192; }
    int c0 = bx * 32, r0 = blockIdx.y * 32;
    int tc = threadIdx.x & 31, tr = threadIdx.x >> 5; // tr 0..7
#pragma unroll
    for (int i = 0; i < 32; i += 8)
        tile[tr + i][tc] = src[(size_t)(r0 + tr + i) * ld_s + c0 + tc];
    __syncthreads();
#pragma unroll
    for (int i = 0; i < 32; i += 8)
        dst[(size_t)(c0 + tr + i) * ld_d + r0 + tc] = f2bf(tile[tc][tr + i]);
}

// ---------------- causal softmax over bf16 scores, in place ----------------
__global__ __launch_bounds__(256) void softmax_causal(unsigned short* __restrict__ sc) {
    int r = blockIdx.x;            // 0..8191 = b*2048+s
    int s = r & (S_LEN - 1);
    unsigned short* row = sc + (size_t)r * S_LEN;
    int tid = threadIdx.x;
    ushort8 u = *(const ushort8*)(row + tid * 8);
    float v[8];
    float mx = -3.0e38f;
#pragma unroll
    for (int e = 0; e < 8; e++) {
        int t = tid * 8 + e;
        float f = bf2f(u[e]);
        v[e] = (t <= s) ? f : -3.0e38f;
        mx = fmaxf(mx, v[e]);
    }
    for (int off = 32; off > 0; off >>= 1) mx = fmaxf(mx, __shfl_down(mx, off));
    __shared__ float red[8];
    int wave = tid >> 6, lane = tid & 63;
    if (lane == 0) red[wave] = mx;
    __syncthreads();
    mx = fmaxf(fmaxf(red[0], red[1]), fmaxf(red[2], red[3]));
    float ex[8];
    float sum = 0.f;
#pragma unroll
    for (int e = 0; e < 8; e++) {
        ex[e] = (v[e] > -1.0e38f) ? __expf(v[e] - mx) : 0.f;
        sum += ex[e];
    }
    for (int off = 32; off > 0; off >>= 1) sum += __shfl_down(sum, off);
    if (lane == 0) red[4 + wave] = sum;
    __syncthreads();
    float inv = 1.0f / (red[4] + red[5] + red[6] + red[7]);
#pragma unroll
    for (int e = 0; e < 8; e++) {
        row[tid * 8 + e] = f2bf(ex[e] * inv);
    }
}

// ---------------- NT GEMM: C[m,n] = sum_k A[m,k] * Bt[n,k] ----------------
// TM x 128 tile (TM = 128 or 64), BK=64 (two k-half panels), 4 waves (2x2).
// TM=128: per-wave 64x64 = 4x4 MFMA accs. TM=64: per-wave 32x64 = 2x4 accs.
// EPI 0: bf16 store. EPI 1: bf16 store * scale. EPI 2: fp32 store + residual.
// EPI 3: bf16 store for n<4096 (q,k), packed-transposed store into vt for n>=4096 (v).
// causal 0: none. 1: skip fully-masked blocks (scores). 2: clip K at (by+1)*TM (PV).
// causal!=0 remaps by longest-first.
template <int EPI, int TM>
__global__ __launch_bounds__(256) void gemm_nt(
    const unsigned short* __restrict__ Ab, int lda, long sAz,
    const unsigned short* __restrict__ Bb, int ldb, long sBz,
    void* __restrict__ Cb, int ldc, long sCz,
    int kdim, int causal, float scale, const float* __restrict__ resid,
    unsigned short* __restrict__ vt) {
    constexpr int MI = TM / 32;         // A-frag count per wave (4 or 2)
    constexpr int AIW = TM / 64;        // A staging instrs per wave per h (2 or 1)
    int bx = blockIdx.x, by = blockIdx.y, bz = blockIdx.z;
    if (causal) by = gridDim.y - 1 - by;   // longest-first dispatch
    if (causal == 1 && bx * 128 >= (by + 1) * TM) return;
    const unsigned short* A = Ab + (size_t)bz * sAz;
    const unsigned short* Bt = Bb + (size_t)bz * sBz;
    int kmax = kdim;
    if (causal == 2) { int km = (by + 1) * TM; if (km < kmax) kmax = km; }
    int m0 = by * TM, n0 = bx * 128;

    // k-half panels: elem (row r, k kk) at [ (kk>>5)*(rows*32) + r*32 + (kk&31) ]
    __shared__ unsigned short lA[TM * 64];
    __shared__ unsigned short lB[128 * 64];

    int tid = threadIdx.x;
    int wave = tid >> 6, lane = tid & 63;
    int quad = lane >> 4, l16 = lane & 15;
    int wr = wave >> 1, wc = wave & 1;

    // staging: one gload instr covers 16 rows x 32 k (lane -> row +lane>>2, k (lane&3)*8)
    int rlane = lane >> 2;
    int ck = (lane & 3) * 8;
    const unsigned short* gA[AIW][2];
    const unsigned short* gB[2][2];
    unsigned short* ldA[AIW][2];
    unsigned short* ldB[2][2];
#pragma unroll
    for (int h = 0; h < 2; h++) {
#pragma unroll
        for (int r16 = 0; r16 < AIW; r16++) {
            int arow = wave * (TM / 4) + r16 * 16;
            gA[r16][h] = A + (size_t)(m0 + arow + rlane) * lda + h * 32 + ck;
            ldA[r16][h] = &lA[h * (TM * 32) + arow * 32];
        }
#pragma unroll
        for (int r16 = 0; r16 < 2; r16++) {
            int brow = wave * 32 + r16 * 16;
            gB[r16][h] = Bt + (size_t)(n0 + brow + rlane) * ldb + h * 32 + ck;
            ldB[r16][h] = &lB[h * 4096 + brow * 32];
        }
    }

    f32x4 acc[MI][4] = {};

    for (int k0 = 0; k0 < kmax; k0 += 64) {
        __syncthreads();
#pragma unroll
        for (int h = 0; h < 2; h++) {
#pragma unroll
            for (int r16 = 0; r16 < AIW; r16++) gload_lds16(gA[r16][h], ldA[r16][h]);
#pragma unroll
            for (int r16 = 0; r16 < 2; r16++) gload_lds16(gB[r16][h], ldB[r16][h]);
        }
        __syncthreads();
#pragma unroll
        for (int h = 0; h < 2; h++) {
            short8 af[MI], bfr[4];
#pragma unroll
            for (int i = 0; i < MI; i++)
                af[i] = *(const short8*)&lA[h * (TM * 32) + (wr * (TM / 2) + i * 16 + l16) * 32 + quad * 8];
#pragma unroll
            for (int j = 0; j < 4; j++)
                bfr[j] = *(const short8*)&lB[h * 4096 + (wc * 64 + j * 16 + l16) * 32 + quad * 8];
#pragma unroll
            for (int i = 0; i < MI; i++)
#pragma unroll
                for (int j = 0; j < 4; j++)
                    acc[i][j] = __builtin_amdgcn_mfma_f32_16x16x32_bf16(af[i], bfr[j], acc[i][j], 0, 0, 0);
        }
#pragma unroll
        for (int h = 0; h < 2; h++) {
#pragma unroll
            for (int r16 = 0; r16 < AIW; r16++) gA[r16][h] += 64;
#pragma unroll
            for (int r16 = 0; r16 < 2; r16++) gB[r16][h] += 64;
        }
    }

    // epilogue: C[row = m0+wr*(TM/2)+i*16+quad*4+r][col = n0+wc*64+j*16+l16]
    int row0 = m0 + wr * (TM / 2) + quad * 4;
    int col0 = n0 + wc * 64 + l16;
    if (EPI == 3 && n0 >= 4096) {
        // v columns: write transposed into vt[batch][kcol][s], packed 4 s-values
        int batch = (m0 + wr * (TM / 2)) >> 11;
        int sl0 = ((m0 + wr * (TM / 2)) & 2047) + quad * 4;
#pragma unroll
        for (int j = 0; j < 4; j++) {
            int kcol = (n0 - 4096) + wc * 64 + j * 16 + l16;
            unsigned short* base = vt + (size_t)batch * S_LEN * S_LEN + (size_t)kcol * S_LEN + sl0;
#pragma unroll
            for (int i = 0; i < MI; i++) {
                ushort4v p;
#pragma unroll
                for (int r = 0; r < 4; r++) p[r] = f2bf(acc[i][j][r]);
                *(ushort4v*)(base + i * 16) = p;
            }
        }
    } else if (EPI == 0 || EPI == 1 || EPI == 3) {
        unsigned short* C = (unsigned short*)Cb + (size_t)bz * sCz;
#pragma unroll
        for (int i = 0; i < MI; i++)
#pragma unroll
            for (int r = 0; r < 4; r++) {
                int row = row0 + i * 16 + r;
#pragma unroll
                for (int j = 0; j < 4; j++) {
                    float v = acc[i][j][r];
                    if (EPI == 1) v *= scale;
                    C[(size_t)row * ldc + col0 + j * 16] = f2bf(v);
                }
            }
    } else {
        float* C = (float*)Cb + (size_t)bz * sCz;
#pragma unroll
        for (int i = 0; i < MI; i++)
#pragma unroll
            for (int r = 0; r < 4; r++) {
                int row = row0 + i * 16 + r;
#pragma unroll
                for (int j = 0; j < 4; j++) {
                    int col = col0 + j * 16;
                    C[(size_t)row * ldc + col] = acc[i][j][r] + resid[(size_t)row * ldc + col];
                }
            }
    }
}

extern "C" void kernel_launch(void* const* d_in, const int* in_sizes, int n_in,
                              void* d_out, int out_size, void* d_ws, size_t ws_size,
                              hipStream_t stream) {
    const float* x      = (const float*)d_in[0];   // [4,2048,2048]
    const float* qkv    = (const float*)d_in[1];   // [2048,6144]
    const float* o_proj = (const float*)d_in[2];   // [2048,2048]
    const float* gamma  = (const float*)d_in[3];
    const float* beta   = (const float*)d_in[4];
    float* out = (float*)d_out;                    // [8192,2048]

    char* w = (char*)d_ws;
    unsigned short* xn      = (unsigned short*)(w);              // 33,554,432 B [8192,2048]; later aliased as scores
    unsigned short* w_t     = (unsigned short*)(w + 33554432);   // 25,165,824 B [6144,2048] qkv^T
    unsigned short* o_t     = (unsigned short*)(w + 58720256);   //  8,388,608 B [2048,2048] o_proj^T
    unsigned short* qkv_out = (unsigned short*)(w + 67108864);   // 100,663,296 B [8192,6144] q|k (q slot reused for attn_out)
    unsigned short* v_t     = (unsigned short*)(w + 167772160);  // 33,554,432 B [4][2048,2048] v^T (written by GEMM1 epilogue)
    unsigned short* scores  = xn;                                // alias: x_norm dead after GEMM1

    // 1) LayerNorm + cast
    ln_kernel<<<NROWS, 256, 0, stream>>>(x, gamma, beta, xn);
    // 2) weight transposes + cast (one launch)
    transp_weights<<<dim3(256, 64), 256, 0, stream>>>(qkv, w_t, o_proj, o_t);
    // 3) QKV projection: [8192,2048] @ [2048,6144]; q,k row-major bf16, v written transposed to v_t
    gemm_nt<3, 128><<<dim3(48, 64, 1), 256, 0, stream>>>(xn, HD, 0L, w_t, HD, 0L,
        (void*)qkv_out, N3, 0L, HD, 0, 1.0f, nullptr, v_t);
    // 4) scores = q @ k^T * scale (TM=64: 1088 active blocks, longest-first)
    float scale = 0.022097086912079608f; // 1/sqrt(2048)
    gemm_nt<1, 64><<<dim3(16, 32, 4), 256, 0, stream>>>(qkv_out, N3, (long)S_LEN * N3,
        qkv_out + 2048, N3, (long)S_LEN * N3,
        (void*)scores, S_LEN, (long)S_LEN * S_LEN, HD, 1, scale, nullptr, nullptr);
    // 5) causal softmax in place (zeroes t>s so PV GEMM reads clean zeros)
    softmax_causal<<<NROWS, 256, 0, stream>>>(scores);
    // 6) attn_out = P @ V (TM=64: 2048 blocks, K clipped at (by+1)*64, longest-first)
    gemm_nt<0, 64><<<dim3(16, 32, 4), 256, 0, stream>>>(scores, S_LEN, (long)S_LEN * S_LEN,
        v_t, S_LEN, (long)HD * S_LEN,
        (void*)qkv_out, N3, (long)S_LEN * N3, S_LEN, 2, 1.0f, nullptr, nullptr);
    // 7) out = attn_out @ o_proj + x (fp32)
    gemm_nt<2, 128><<<dim3(16, 64, 1), 256, 0, stream>>>(qkv_out, N3, 0L, o_t, HD, 0L,
        (void*)out, HD, 0L, HD, 0, 1.0f, x, nullptr);
}